// Round 2
// baseline (2159.746 us; speedup 1.0000x reference)
//
#include <hip/hip_runtime.h>
#include <hip/hip_bf16.h>

typedef unsigned short u16;
typedef unsigned int   u32;
typedef __attribute__((ext_vector_type(8))) __bf16 bf16x8;
typedef __attribute__((ext_vector_type(4))) float  f32x4;
typedef __attribute__((ext_vector_type(4))) u16    u16x4;
typedef __attribute__((ext_vector_type(8))) u16    u16x8;

#define NN   1024
#define TT   64
#define LL   62
#define CIN  32
#define COUT 32

__device__ __forceinline__ u16 f2bf(float f){
  u32 u = __builtin_bit_cast(u32, f);
  return (u16)((u + 0x7fffu + ((u >> 16) & 1u)) >> 16);   // RNE
}
__device__ __forceinline__ bf16x8 ld8(const u16* p){ return *(const bf16x8*)p; }

#define MFMA16(a,b,c) __builtin_amdgcn_mfma_f32_16x16x32_bf16((a),(b),(c),0,0,0)
#define GLL16(g,l) __builtin_amdgcn_global_load_lds((const __attribute__((address_space(1))) void*)(g), (__attribute__((address_space(3))) void*)(l), 16, 0, 0)

// ---------- supports -> bf16 ----------
__global__ __launch_bounds__(256) void k_cvt_supports(const float* __restrict__ s0, const float* __restrict__ s1,
                                                      const float* __restrict__ s2, const float* __restrict__ s3,
                                                      u16* __restrict__ Sb){
  const float* srcs[4] = {s0, s1, s2, s3};
  const float* sp = srcs[blockIdx.y];
  u32 i = blockIdx.x * 256u + threadIdx.x;
  Sb[(size_t)blockIdx.y * (size_t)(NN*NN) + i] = f2bf(sp[i]);
}

// ---------- fold weights, BN constants ----------
__global__ __launch_bounds__(256) void k_prep_weights(const float* __restrict__ Wg, const float* __restrict__ Wm,
    const float* __restrict__ W1, const float* __restrict__ gamma, const float* __restrict__ beta,
    const float* __restrict__ rmean, const float* __restrict__ rvar,
    u16* __restrict__ WgB, u16* __restrict__ WmB, u16* __restrict__ W1B,
    float* __restrict__ scl, float* __restrict__ sft){
  int tid = threadIdx.x;
  // Wg_eff: k<32 -> Wg[:,3c]-Wg[:,3c+2] (xt term, identity Cheby + folded -X of L2)
  //         32..63 -> Wg[:,3c+1] (P_S), 64..95 -> 2*Wg[:,3c+2] (Q_S)
  for (int i = tid; i < 64*96; i += 256){
    int o = i / 96, k = i - o*96;
    float v;
    if (k < 32)      v = Wg[o*96 + 3*k] - Wg[o*96 + 3*k + 2];
    else if (k < 64) v = Wg[o*96 + 3*(k-32) + 1];
    else             v = 2.0f * Wg[o*96 + 3*(k-64) + 2];
    WgB[i] = f2bf(v);
  }
  for (int i = tid; i < 64*224; i += 256) WmB[i] = f2bf(Wm[i]);
  for (int i = tid; i < 64*32;  i += 256) W1B[i] = f2bf(W1[i]);
  if (tid < 64){
    float inv = gamma[tid] * rsqrtf(rvar[tid] + 1e-5f);
    scl[tid] = inv;
    sft[tid] = beta[tid] - rmean[tid]*inv;
  }
}

// ---------- time conv (VALID, Kt=3) + node-major xt + node-major residual src ----------
__global__ __launch_bounds__(256) void k_timeconv(const float* __restrict__ x, const float* __restrict__ Wt,
                                                  const float* __restrict__ bt,
                                                  u16* __restrict__ xtN, u16* __restrict__ xtnm,
                                                  u16* __restrict__ resnm, int b0){
  __shared__ float xl[CIN][TT];        // 8 KB
  __shared__ float wl[COUT*CIN*3];     // 12 KB
  __shared__ float btl[COUT];
  const int n = blockIdx.x, bl = blockIdx.y, b = b0 + bl;
  const int tid = threadIdx.x;
  for (int i = tid; i < CIN*TT; i += 256){
    int ci = i >> 6, t = i & 63;
    xl[ci][t] = x[((size_t)(b*CIN + ci)*NN + n)*TT + t];
  }
  for (int i = tid; i < COUT*CIN*3; i += 256) wl[i] = Wt[i];
  if (tid < COUT) btl[tid] = bt[tid];
  __syncthreads();
  const int l = tid >> 2, oq = tid & 3;
  if (l < LL){
    const size_t nb = ((size_t)bl*NN + n)*1984;
    u16x8 tv, rv;
    #pragma unroll
    for (int oo = 0; oo < 8; ++oo){
      const int o = oq*8 + oo;
      float acc = btl[o];
      const float* w = &wl[o*CIN*3];
      #pragma unroll 8
      for (int ci = 0; ci < CIN; ++ci){
        acc += xl[ci][l]*w[0] + xl[ci][l+1]*w[1] + xl[ci][l+2]*w[2];
        w += 3;
      }
      u16 hv = f2bf(acc);
      tv[oo] = hv;
      xtN[((size_t)(bl*COUT + o)*NN + n)*LL + l] = hv;   // natural layout for k_transpose
      rv[oo] = f2bf(xl[o][2 + l]);                        // residual source x[b][c][n][2+l]
    }
    *(u16x8*)(xtnm  + nb + l*32 + oq*8) = tv;            // node-major, coalesced 16B
    *(u16x8*)(resnm + nb + l*32 + oq*8) = rv;
  }
}

// ---------- transpose xt_nat -> Xp[m=(bl*62+l)*32+c][n] ----------
__global__ __launch_bounds__(256) void k_transpose(const u16* __restrict__ xtN, u16* __restrict__ Xp){
  __shared__ u16 tile[64][66];
  const int nt = blockIdx.x, c = blockIdx.y, bl = blockIdx.z;
  const int n0 = nt * 64;
  const int tid = threadIdx.x;
  const u16* src = xtN + ((size_t)(bl*COUT + c)*NN + n0)*LL;
  for (int i = tid; i < 64*31; i += 256){        // 64 rows x 31 dwords
    int r = i / 31, d = i - r*31;
    u32 v = *(const u32*)(src + (size_t)r*LL + 2*d);
    *(u32*)&tile[r][2*d] = v;
  }
  __syncthreads();
  for (int i = tid; i < LL*32; i += 256){        // 62 l x 32 dword-pairs of n
    int l = i >> 5, np = i & 31;
    u32 v = (u32)tile[2*np][l] | ((u32)tile[2*np+1][l] << 16);
    *(u32*)(Xp + ((size_t)((bl*LL + l)*32 + c))*NN + n0 + 2*np) = v;
  }
}

// ---------- graph GEMM: C[m][w] = sum_v A[m][v] * S_j[w][v]  (128x128 tile, BK=32) ----------
template<bool WRITE_PM>
__global__ __launch_bounds__(256) void k_gemm(const u16* __restrict__ Abase, const u16* __restrict__ Sb,
                                              u16* __restrict__ pm, u16* __restrict__ nm,
                                              int Mc, int Astride){
  __shared__ u16 Alds[128*32];
  __shared__ u16 Blds[128*32];
  const int j = blockIdx.z;
  const u16* A  = Abase + (size_t)j * (size_t)Astride;
  const u16* Bm = Sb + (size_t)j * (size_t)(NN*NN);
  const int m0 = blockIdx.x * 128, w0 = blockIdx.y * 128;
  const int tid = threadIdx.x, wid = tid >> 6;
  const int lane = tid & 63, fc = lane & 15, fh = lane >> 4;
  const int srow = tid >> 2, sch = tid & 3;
  const u16* gA0 = A  + (size_t)(m0 + srow)      * NN + sch*8;
  const u16* gA1 = A  + (size_t)(m0 + srow + 64) * NN + sch*8;
  const u16* gB0 = Bm + (size_t)(w0 + srow)      * NN + sch*8;
  const u16* gB1 = Bm + (size_t)(w0 + srow + 64) * NN + sch*8;
  u16* lA0 = Alds + wid*512;        u16* lA1 = Alds + 2048 + wid*512;
  u16* lB0 = Blds + wid*512;        u16* lB1 = Blds + 2048 + wid*512;
  const int wm = wid >> 1, wn = wid & 1;
  f32x4 acc[4][4] = {};
  for (int v0 = 0; v0 < NN; v0 += 32){
    GLL16(gA0 + v0, lA0);
    GLL16(gA1 + v0, lA1);
    GLL16(gB0 + v0, lB0);
    GLL16(gB1 + v0, lB1);
    __syncthreads();
    bf16x8 af[4], bf_[4];
    #pragma unroll
    for (int i = 0; i < 4; ++i){
      af[i]  = ld8(&Alds[(wm*64 + i*16 + fc)*32 + fh*8]);
      bf_[i] = ld8(&Blds[(wn*64 + i*16 + fc)*32 + fh*8]);
    }
    #pragma unroll
    for (int i = 0; i < 4; ++i)
      #pragma unroll
      for (int q = 0; q < 4; ++q)
        acc[i][q] = MFMA16(af[i], bf_[q], acc[i][q]);
    __syncthreads();
  }
  if (WRITE_PM){
    u16* pmj = pm + (size_t)j * (size_t)Mc * NN;
    #pragma unroll
    for (int i = 0; i < 4; ++i){
      int mb = m0 + wm*64 + i*16 + 4*fh;
      #pragma unroll
      for (int q = 0; q < 4; ++q){
        int wc = w0 + wn*64 + q*16 + fc;
        #pragma unroll
        for (int r = 0; r < 4; ++r)
          pmj[(size_t)(mb + r)*NN + wc] = f2bf(acc[i][q][r]);
      }
    }
  }
  {
    u16* nmj = nm + (size_t)j * (size_t)Mc * NN;
    #pragma unroll
    for (int i = 0; i < 4; ++i){
      int mb = m0 + wm*64 + i*16 + 4*fh;
      #pragma unroll
      for (int q = 0; q < 4; ++q){
        int wc = w0 + wn*64 + q*16 + fc;
        u16x4 pk = { f2bf(acc[i][q][0]), f2bf(acc[i][q][1]), f2bf(acc[i][q][2]), f2bf(acc[i][q][3]) };
        *(u16x4*)&nmj[(size_t)wc*Mc + mb] = pk;   // 4 consecutive m per lane
      }
    }
  }
}

// ---------- final: LDS-free channel-mix MFMA + GLU + residual + BN ----------
__global__ __launch_bounds__(256) void k_final(
    const u16* __restrict__ xtnm, const u16* __restrict__ resnm,
    const u16* __restrict__ Pnm, const u16* __restrict__ Qnm,
    const u16* __restrict__ WgB, const u16* __restrict__ WmB, const u16* __restrict__ W1B,
    const float* __restrict__ bg, const float* __restrict__ bm, const float* __restrict__ b1,
    const float* __restrict__ scl, const float* __restrict__ sft,
    float* __restrict__ out, int b0, int Mc){
  const int n = blockIdx.x, bl = blockIdx.y, b = b0 + bl;
  const int tid = threadIdx.x, wid = tid >> 6, lane = tid & 63;
  const int fc = lane & 15, fh = lane >> 4;
  const int lcol = wid*16 + fc;                      // this lane's D column = l
  const size_t off   = (size_t)lcol*32 + fh*8;       // u16 offset inside a [l][c] slab
  const size_t nb    = ((size_t)bl*NN + n)*1984;
  const size_t pqoff = (size_t)n*Mc + (size_t)bl*1984 + off;
  const size_t jstr  = (size_t)NN*Mc;

  // 10 coalesced 16B fragment loads (one per branch), issued up front
  bf16x8 bX  = ld8(xtnm  + nb + off);
  bf16x8 bR  = ld8(resnm + nb + off);
  bf16x8 bPS = ld8(Pnm + pqoff);
  bf16x8 bQS = ld8(Qnm + pqoff);
  bf16x8 bP0 = ld8(Pnm + jstr   + pqoff);
  bf16x8 bQ0 = ld8(Qnm + jstr   + pqoff);
  bf16x8 bP1 = ld8(Pnm + 2*jstr + pqoff);
  bf16x8 bQ1 = ld8(Qnm + 2*jstr + pqoff);
  bf16x8 bP2 = ld8(Pnm + 3*jstr + pqoff);
  bf16x8 bQ2 = ld8(Qnm + 3*jstr + pqoff);

  f32x4 acc[12];
  #pragma unroll
  for (int i = 0; i < 12; ++i) acc[i] = (f32x4){0.f, 0.f, 0.f, 0.f};

  {                                            // u1: K over {X, P_S, Q_S}
    const bf16x8 u1b[3] = {bX, bPS, bQS};
    #pragma unroll
    for (int s = 0; s < 3; ++s)
      #pragma unroll
      for (int t = 0; t < 4; ++t)
        acc[t] = MFMA16(ld8(WgB + (t*16 + fc)*96 + s*32 + 8*fh), u1b[s], acc[t]);
  }
  {                                            // u2: K over {X, P0,Q0,P1,Q1,P2,Q2}
    const bf16x8 u2b[7] = {bX, bP0, bQ0, bP1, bQ1, bP2, bQ2};
    #pragma unroll
    for (int s = 0; s < 7; ++s)
      #pragma unroll
      for (int t = 0; t < 4; ++t)
        acc[4+t] = MFMA16(ld8(WmB + (t*16 + fc)*224 + s*32 + 8*fh), u2b[s], acc[4+t]);
  }
  #pragma unroll
  for (int t = 0; t < 4; ++t)                  // r: K over {xres}
    acc[8+t] = MFMA16(ld8(W1B + (t*16 + fc)*32 + 8*fh), bR, acc[8+t]);

  if (lcol < LL){
    float* ob = out + ((size_t)b*64*NN + n)*LL + lcol;
    #pragma unroll
    for (int t = 0; t < 2; ++t){
      #pragma unroll
      for (int r = 0; r < 4; ++r){
        int os = t*16 + 4*fh + r;              // 0..31
        float u1a = acc[t][r]   + bg[os];
        float u1b = acc[t+2][r] + bg[os+32];
        float s1  = fmaxf(u1a, 0.f) / (1.f + __expf(-u1b));
        float z1  = s1 + acc[8+t][r] + b1[os];
        ob[(size_t)os*(NN*LL)] = z1*scl[os] + sft[os];
        int o2 = 32 + os;
        float u2a = acc[4+t][r] + bm[os];
        float u2b = acc[6+t][r] + bm[os+32];
        float s2  = fmaxf(u2a, 0.f) / (1.f + __expf(-u2b));
        float z2  = s2 + acc[10+t][r] + b1[o2];
        ob[(size_t)o2*(NN*LL)] = z2*scl[o2] + sft[o2];
      }
    }
  }
}

extern "C" void kernel_launch(void* const* d_in, const int* in_sizes, int n_in,
                              void* d_out, int out_size, void* d_ws, size_t ws_size,
                              hipStream_t stream){
  const float* x    = (const float*)d_in[0];
  const float* sup  = (const float*)d_in[1];
  const float* sup0 = (const float*)d_in[2];
  const float* sup1 = (const float*)d_in[3];
  const float* sup2 = (const float*)d_in[4];
  const float* W1   = (const float*)d_in[5];
  const float* b1   = (const float*)d_in[6];
  const float* Wt   = (const float*)d_in[7];
  const float* bt   = (const float*)d_in[8];
  const float* Wg   = (const float*)d_in[9];
  const float* bg   = (const float*)d_in[10];
  const float* Wm   = (const float*)d_in[11];
  const float* bm   = (const float*)d_in[12];
  const float* gam  = (const float*)d_in[13];
  const float* bet  = (const float*)d_in[14];
  const float* rme  = (const float*)d_in[15];
  const float* rva  = (const float*)d_in[16];
  float* out = (float*)d_out;

  char* p = (char*)d_ws;
  auto carve = [&](size_t bytes)->char*{
    char* r = p; p += (bytes + 255) & ~(size_t)255; return r;
  };
  u16*   Sb  = (u16*)carve((size_t)4*NN*NN*2);
  u16*   WgB = (u16*)carve(64*96*2);
  u16*   WmB = (u16*)carve(64*224*2);
  u16*   W1B = (u16*)carve(64*32*2);
  float* scl = (float*)carve(64*4);
  float* sft = (float*)carve(64*4);
  size_t used = (size_t)(p - (char*)d_ws);

  const size_t unit = 4063232ull;             // 32*1024*62*2 bytes per batch per big buffer
  int CB = 16;
  while (CB > 2 && used + 16ull*CB*unit + (1u<<20) > ws_size) CB >>= 1;
  size_t bufB = (size_t)CB * unit;
  u16* xtN   = (u16*)carve(bufB);
  u16* xtnm  = (u16*)carve(bufB + 4096);       // +4KB guard: k_final reads l up to 63
  u16* resnm = (u16*)carve(bufB + 4096);
  u16* Xp    = (u16*)carve(bufB);
  u16* Ppm   = (u16*)carve(4*bufB);
  u16* Pnm   = (u16*)carve(4*bufB + 4096);
  u16* Qnm   = (u16*)carve(4*bufB + 4096);
  int Mc = CB * 1984;

  k_cvt_supports<<<dim3(4096, 4), 256, 0, stream>>>(sup, sup0, sup1, sup2, Sb);
  k_prep_weights<<<1, 256, 0, stream>>>(Wg, Wm, W1, gam, bet, rme, rva, WgB, WmB, W1B, scl, sft);

  for (int b0 = 0; b0 < 16; b0 += CB){
    k_timeconv <<<dim3(1024, CB), 256, 0, stream>>>(x, Wt, bt, xtN, xtnm, resnm, b0);
    k_transpose<<<dim3(16, 32, CB), 256, 0, stream>>>(xtN, Xp);
    k_gemm<true ><<<dim3(Mc/128, 8, 4), 256, 0, stream>>>(Xp,  Sb, Ppm, Pnm, Mc, 0);
    k_gemm<false><<<dim3(Mc/128, 8, 4), 256, 0, stream>>>(Ppm, Sb, (u16*)nullptr, Qnm, Mc, Mc*NN);
    k_final    <<<dim3(1024, CB), 256, 0, stream>>>(xtnm, resnm, Pnm, Qnm, WgB, WmB, W1B,
                                                    bg, bm, b1, scl, sft, out, b0, Mc);
  }
}

// Round 3
// 1247.680 us; speedup vs baseline: 1.7310x; 1.7310x over previous
//
#include <hip/hip_runtime.h>
#include <hip/hip_bf16.h>

typedef unsigned short u16;
typedef unsigned int   u32;
typedef unsigned long long u64;
typedef __attribute__((ext_vector_type(8))) __bf16 bf16x8;
typedef __attribute__((ext_vector_type(4))) float  f32x4;
typedef __attribute__((ext_vector_type(4))) u16    u16x4;
typedef __attribute__((ext_vector_type(8))) u16    u16x8;

#define NN   1024
#define TT   64
#define LL   62
#define CIN  32
#define COUT 32

__device__ __forceinline__ u16 f2bf(float f){
  u32 u = __builtin_bit_cast(u32, f);
  return (u16)((u + 0x7fffu + ((u >> 16) & 1u)) >> 16);   // RNE
}
__device__ __forceinline__ bf16x8 ld8(const u16* p){ return *(const bf16x8*)p; }
// 4-byte-aligned LDS read of 8 bf16 (row stride not 16B-aligned)
__device__ __forceinline__ bf16x8 ld8_u32(const u16* p){
  union { bf16x8 v; u32 w[4]; } u;
  #pragma unroll
  for (int e = 0; e < 4; ++e) u.w[e] = *(const u32*)(p + 2*e);
  return u.v;
}

#define MFMA16(a,b,c) __builtin_amdgcn_mfma_f32_16x16x32_bf16((a),(b),(c),0,0,0)
#define GLL16(g,l) __builtin_amdgcn_global_load_lds((const __attribute__((address_space(1))) void*)(g), (__attribute__((address_space(3))) void*)(l), 16, 0, 0)

// ---------- supports -> bf16, row-major slab (2j) + transposed copy ----------
__global__ __launch_bounds__(256) void k_cvt_supports(const float* __restrict__ s0, const float* __restrict__ s1,
                                                      const float* __restrict__ s2, const float* __restrict__ s3,
                                                      u16* __restrict__ Sb8, u16* __restrict__ STb){
  __shared__ u16 t16[64][66];
  const float* srcs[4] = {s0, s1, s2, s3};
  const int j = blockIdx.z;
  const float* sp = srcs[j];
  const int u0 = blockIdx.y * 64, v0 = blockIdx.x * 64;
  const int tid = threadIdx.x;
  u16* SbJ = Sb8 + (size_t)(2*j) * (size_t)(NN*NN);
  u16* STJ = STb + (size_t)j * (size_t)(NN*NN);
  for (int i = tid; i < 4096; i += 256){
    int r = i >> 6, c = i & 63;
    u16 h = f2bf(sp[(size_t)(u0+r)*NN + v0 + c]);
    SbJ[(size_t)(u0+r)*NN + v0 + c] = h;
    t16[r][c] = h;
  }
  __syncthreads();
  for (int i = tid; i < 4096; i += 256){
    int r = i >> 6, c = i & 63;              // output row v=v0+r, col u=u0+c
    STJ[(size_t)(v0+r)*NN + u0 + c] = t16[c][r];
  }
}

// ---------- fold weights, BN constants ----------
__global__ __launch_bounds__(256) void k_prep_weights(const float* __restrict__ Wg, const float* __restrict__ Wm,
    const float* __restrict__ W1, const float* __restrict__ Wt,
    const float* __restrict__ gamma, const float* __restrict__ beta,
    const float* __restrict__ rmean, const float* __restrict__ rvar,
    u16* __restrict__ WgB, u16* __restrict__ WmB, u16* __restrict__ W1B, u16* __restrict__ WtB,
    float* __restrict__ scl, float* __restrict__ sft){
  int tid = threadIdx.x;
  // Wg_eff: k<32 -> Wg[:,3c]-Wg[:,3c+2] (xt term: identity Cheby + folded -X of L2)
  //         32..63 -> Wg[:,3c+1] (X*S^T), 64..95 -> 2*Wg[:,3c+2] (X*(S^2)^T)
  for (int i = tid; i < 64*96; i += 256){
    int o = i / 96, k = i - o*96;
    float v;
    if (k < 32)      v = Wg[o*96 + 3*k] - Wg[o*96 + 3*k + 2];
    else if (k < 64) v = Wg[o*96 + 3*(k-32) + 1];
    else             v = 2.0f * Wg[o*96 + 3*(k-64) + 2];
    WgB[i] = f2bf(v);
  }
  for (int i = tid; i < 64*224; i += 256) WmB[i] = f2bf(Wm[i]);
  for (int i = tid; i < 64*32;  i += 256) W1B[i] = f2bf(W1[i]);
  // WtB[o][k*32+ci] = Wt[o][ci][k]  (K-dim reordered: k outer, ci inner)
  for (int i = tid; i < 32*96; i += 256){
    int o = i / 96, kk = i - o*96;
    int k = kk >> 5, ci = kk & 31;
    WtB[i] = f2bf(Wt[(o*32 + ci)*3 + k]);
  }
  if (tid < 64){
    float inv = gamma[tid] * rsqrtf(rvar[tid] + 1e-5f);
    scl[tid] = inv;
    sft[tid] = beta[tid] - rmean[tid]*inv;
  }
}

// ---------- time conv via MFMA: xtnm[bl][n][l][c] + resnm ----------
__global__ __launch_bounds__(256) void k_timeconv(const float* __restrict__ x, const u16* __restrict__ WtB,
                                                  const float* __restrict__ bt,
                                                  u16* __restrict__ xtnm, u16* __restrict__ resnm, int b0){
  __shared__ u16 xs[68][34];                 // [t][ci], pad 2, +4 guard rows
  const int n = blockIdx.x, bl = blockIdx.y, b = b0 + bl;
  const int tid = threadIdx.x;
  for (int i = tid; i < 2048; i += 256){
    int ci = i >> 6, t = i & 63;
    xs[t][ci] = f2bf(x[((size_t)(b*CIN + ci)*NN + n)*TT + t]);
  }
  if (tid < 136) xs[64 + tid/34][tid % 34] = 0;   // zero guard rows 64..67
  __syncthreads();
  const int wid = tid >> 6, lane = tid & 63, fc = lane & 15, fh = lane >> 4;
  const int lcol = wid*16 + fc;              // D column = l (0..63; <62 valid)
  f32x4 acc0 = {0.f,0.f,0.f,0.f}, acc1 = {0.f,0.f,0.f,0.f};
  #pragma unroll
  for (int s = 0; s < 3; ++s){
    bf16x8 bv = ld8_u32(&xs[lcol + s][8*fh]);
    acc0 = MFMA16(ld8(WtB + fc*96        + s*32 + 8*fh), bv, acc0);
    acc1 = MFMA16(ld8(WtB + (16+fc)*96   + s*32 + 8*fh), bv, acc1);
  }
  const size_t nb = ((size_t)bl*NN + n)*1984;
  for (int i = tid; i < LL*4; i += 256){     // residual: x[b][c][n][2+l] node-major
    int l = i >> 2, oq = i & 3;
    union { bf16x8 v; u16x8 h; } u; u.v = ld8_u32(&xs[2 + l][oq*8]);
    *(u16x8*)(resnm + nb + (size_t)l*32 + oq*8) = u.h;
  }
  if (lcol < LL){
    #pragma unroll
    for (int t = 0; t < 2; ++t){
      const f32x4& a = t ? acc1 : acc0;
      u16x4 pk;
      #pragma unroll
      for (int r = 0; r < 4; ++r) pk[r] = f2bf(a[r] + bt[t*16 + 4*fh + r]);
      *(u16x4*)(xtnm + nb + (size_t)lcol*32 + t*16 + 4*fh) = pk;
    }
  }
}

// ---------- transpose xtnm -> Xp[m=(bl*62+l)*32+c][n] ----------
__global__ __launch_bounds__(256) void k_transpose(const u16* __restrict__ xtnm, u16* __restrict__ Xp){
  __shared__ u32 t32[4][64][17];
  const int nt = blockIdx.x, lq = blockIdx.y, bl = blockIdx.z;
  const int n0 = nt*64, l0 = lq*4;
  const int tid = threadIdx.x;
  for (int i = tid; i < 1024; i += 256){           // 4 l x 64 n x 4 (8c units)
    int li = i >> 8, rem = i & 255, j = rem >> 2, oq = rem & 3;
    int l = l0 + li;
    if (l < LL){
      const u16* src = xtnm + ((size_t)bl*NN + n0 + j)*1984 + (size_t)l*32 + oq*8;
      u16x8 v = *(const u16x8*)src;
      u32* d = &t32[li][j][oq*4];
      d[0] = (u32)v[0] | ((u32)v[1] << 16);
      d[1] = (u32)v[2] | ((u32)v[3] << 16);
      d[2] = (u32)v[4] | ((u32)v[5] << 16);
      d[3] = (u32)v[6] | ((u32)v[7] << 16);
    }
  }
  __syncthreads();
  for (int i = tid; i < 1024; i += 256){           // 4 l x 32 c x 8 (8n units)
    int li = i >> 8, rem = i & 255, c = rem >> 3, np = rem & 7;
    int l = l0 + li;
    if (l < LL){
      int cw = c >> 1, hi = c & 1;
      u16x8 o;
      #pragma unroll
      for (int e = 0; e < 8; ++e){
        u32 w = t32[li][np*8 + e][cw];
        o[e] = hi ? (u16)(w >> 16) : (u16)w;
      }
      size_t m = ((size_t)bl*LL + l)*32 + c;
      *(u16x8*)(Xp + m*NN + n0 + np*8) = o;
    }
  }
}

// ---------- GEMM: C[m][w] = sum_v A[m][v] * B_j[w][v]  (128x128 tile, BK=32) ----------
// MODE 0: node-major out[j][w*Mc+m] (bf16)   MODE 1: row-major out[j][m*NN+w]
template<int MODE>
__global__ __launch_bounds__(256) void k_gemm(const u16* __restrict__ Abase, u64 Ajstr,
                                              const u16* __restrict__ Bbase, u64 Bjstr,
                                              u16* __restrict__ outp, u64 Ojstr, int Mc){
  __shared__ u16 Alds[128*32];
  __shared__ u16 Blds[128*32];
  const int j = blockIdx.z;
  const u16* A  = Abase + (size_t)j * Ajstr;
  const u16* Bm = Bbase + (size_t)j * Bjstr;
  const int m0 = blockIdx.x * 128, w0 = blockIdx.y * 128;
  const int tid = threadIdx.x, wid = tid >> 6;
  const int lane = tid & 63, fc = lane & 15, fh = lane >> 4;
  const int srow = tid >> 2, sch = tid & 3;
  const u16* gA0 = A  + (size_t)(m0 + srow)      * NN + sch*8;
  const u16* gA1 = A  + (size_t)(m0 + srow + 64) * NN + sch*8;
  const u16* gB0 = Bm + (size_t)(w0 + srow)      * NN + sch*8;
  const u16* gB1 = Bm + (size_t)(w0 + srow + 64) * NN + sch*8;
  u16* lA0 = Alds + wid*512;        u16* lA1 = Alds + 2048 + wid*512;
  u16* lB0 = Blds + wid*512;        u16* lB1 = Blds + 2048 + wid*512;
  const int wm = wid >> 1, wn = wid & 1;
  f32x4 acc[4][4] = {};
  for (int v0 = 0; v0 < NN; v0 += 32){
    GLL16(gA0 + v0, lA0);
    GLL16(gA1 + v0, lA1);
    GLL16(gB0 + v0, lB0);
    GLL16(gB1 + v0, lB1);
    __syncthreads();
    bf16x8 af[4], bf_[4];
    #pragma unroll
    for (int i = 0; i < 4; ++i){
      af[i]  = ld8(&Alds[(wm*64 + i*16 + fc)*32 + fh*8]);
      bf_[i] = ld8(&Blds[(wn*64 + i*16 + fc)*32 + fh*8]);
    }
    #pragma unroll
    for (int i = 0; i < 4; ++i)
      #pragma unroll
      for (int q = 0; q < 4; ++q)
        acc[i][q] = MFMA16(af[i], bf_[q], acc[i][q]);
    __syncthreads();
  }
  u16* oj = outp + (size_t)j * Ojstr;
  if (MODE == 0){
    #pragma unroll
    for (int i = 0; i < 4; ++i){
      int mb = m0 + wm*64 + i*16 + 4*fh;
      #pragma unroll
      for (int q = 0; q < 4; ++q){
        int wc = w0 + wn*64 + q*16 + fc;
        u16x4 pk = { f2bf(acc[i][q][0]), f2bf(acc[i][q][1]), f2bf(acc[i][q][2]), f2bf(acc[i][q][3]) };
        *(u16x4*)&oj[(size_t)wc*Mc + mb] = pk;
      }
    }
  } else {
    #pragma unroll
    for (int i = 0; i < 4; ++i){
      int mb = m0 + wm*64 + i*16 + 4*fh;
      #pragma unroll
      for (int q = 0; q < 4; ++q){
        int wc = w0 + wn*64 + q*16 + fc;
        #pragma unroll
        for (int r = 0; r < 4; ++r)
          oj[(size_t)(mb + r)*NN + wc] = f2bf(acc[i][q][r]);
      }
    }
  }
}

// ---------- final: LDS-free channel-mix MFMA + GLU + residual + BN ----------
__global__ __launch_bounds__(256) void k_final(
    const u16* __restrict__ xtnm, const u16* __restrict__ resnm, const u16* __restrict__ Cnm,
    const u16* __restrict__ WgB, const u16* __restrict__ WmB, const u16* __restrict__ W1B,
    const float* __restrict__ bg, const float* __restrict__ bm, const float* __restrict__ b1,
    const float* __restrict__ scl, const float* __restrict__ sft,
    float* __restrict__ out, int b0, int Mc){
  const int n = blockIdx.x, bl = blockIdx.y, b = b0 + bl;
  const int tid = threadIdx.x, wid = tid >> 6, lane = tid & 63;
  const int fc = lane & 15, fh = lane >> 4;
  const int lcol = wid*16 + fc;                      // this lane's D column = l
  const size_t off   = (size_t)lcol*32 + fh*8;
  const size_t nb    = ((size_t)bl*NN + n)*1984;
  const size_t pqoff = (size_t)n*Mc + (size_t)bl*1984 + off;
  const size_t jstr  = (size_t)NN*Mc;

  bf16x8 bX  = ld8(xtnm  + nb + off);
  bf16x8 bR  = ld8(resnm + nb + off);
  bf16x8 bPS = ld8(Cnm            + pqoff);
  bf16x8 bQS = ld8(Cnm + 1*jstr   + pqoff);
  bf16x8 bP0 = ld8(Cnm + 2*jstr   + pqoff);
  bf16x8 bQ0 = ld8(Cnm + 3*jstr   + pqoff);
  bf16x8 bP1 = ld8(Cnm + 4*jstr   + pqoff);
  bf16x8 bQ1 = ld8(Cnm + 5*jstr   + pqoff);
  bf16x8 bP2 = ld8(Cnm + 6*jstr   + pqoff);
  bf16x8 bQ2 = ld8(Cnm + 7*jstr   + pqoff);

  f32x4 acc[12];
  #pragma unroll
  for (int i = 0; i < 12; ++i) acc[i] = (f32x4){0.f, 0.f, 0.f, 0.f};

  {                                            // u1: K over {X, P_S, Q_S}
    const bf16x8 u1b[3] = {bX, bPS, bQS};
    #pragma unroll
    for (int s = 0; s < 3; ++s)
      #pragma unroll
      for (int t = 0; t < 4; ++t)
        acc[t] = MFMA16(ld8(WgB + (t*16 + fc)*96 + s*32 + 8*fh), u1b[s], acc[t]);
  }
  {                                            // u2: K over {X, P0,Q0,P1,Q1,P2,Q2}
    const bf16x8 u2b[7] = {bX, bP0, bQ0, bP1, bQ1, bP2, bQ2};
    #pragma unroll
    for (int s = 0; s < 7; ++s)
      #pragma unroll
      for (int t = 0; t < 4; ++t)
        acc[4+t] = MFMA16(ld8(WmB + (t*16 + fc)*224 + s*32 + 8*fh), u2b[s], acc[4+t]);
  }
  #pragma unroll
  for (int t = 0; t < 4; ++t)                  // r: K over {xres}
    acc[8+t] = MFMA16(ld8(W1B + (t*16 + fc)*32 + 8*fh), bR, acc[8+t]);

  if (lcol < LL){
    float* ob = out + ((size_t)b*64*NN + n)*LL + lcol;
    #pragma unroll
    for (int t = 0; t < 2; ++t){
      #pragma unroll
      for (int r = 0; r < 4; ++r){
        int os = t*16 + 4*fh + r;              // 0..31
        float u1a = acc[t][r]   + bg[os];
        float u1b = acc[t+2][r] + bg[os+32];
        float s1  = fmaxf(u1a, 0.f) / (1.f + __expf(-u1b));
        float z1  = s1 + acc[8+t][r] + b1[os];
        ob[(size_t)os*(NN*LL)] = z1*scl[os] + sft[os];
        int o2 = 32 + os;
        float u2a = acc[4+t][r] + bm[os];
        float u2b = acc[6+t][r] + bm[os+32];
        float s2  = fmaxf(u2a, 0.f) / (1.f + __expf(-u2b));
        float z2  = s2 + acc[10+t][r] + b1[o2];
        ob[(size_t)o2*(NN*LL)] = z2*scl[o2] + sft[o2];
      }
    }
  }
}

extern "C" void kernel_launch(void* const* d_in, const int* in_sizes, int n_in,
                              void* d_out, int out_size, void* d_ws, size_t ws_size,
                              hipStream_t stream){
  const float* x    = (const float*)d_in[0];
  const float* sup  = (const float*)d_in[1];
  const float* sup0 = (const float*)d_in[2];
  const float* sup1 = (const float*)d_in[3];
  const float* sup2 = (const float*)d_in[4];
  const float* W1   = (const float*)d_in[5];
  const float* b1   = (const float*)d_in[6];
  const float* Wt   = (const float*)d_in[7];
  const float* bt   = (const float*)d_in[8];
  const float* Wg   = (const float*)d_in[9];
  const float* bg   = (const float*)d_in[10];
  const float* Wm   = (const float*)d_in[11];
  const float* bm   = (const float*)d_in[12];
  const float* gam  = (const float*)d_in[13];
  const float* bet  = (const float*)d_in[14];
  const float* rme  = (const float*)d_in[15];
  const float* rva  = (const float*)d_in[16];
  float* out = (float*)d_out;

  char* p = (char*)d_ws;
  auto carve = [&](size_t bytes)->char*{
    char* r = p; p += (bytes + 255) & ~(size_t)255; return r;
  };
  u16*   Sb8 = (u16*)carve((size_t)8*NN*NN*2);   // {S,S^2,A0,A0^2,A1,A1^2,A2,A2^2}
  u16*   STb = (u16*)carve((size_t)4*NN*NN*2);   // transposed raw supports
  u16*   WgB = (u16*)carve(64*96*2);
  u16*   WmB = (u16*)carve(64*224*2);
  u16*   W1B = (u16*)carve(64*32*2);
  u16*   WtB = (u16*)carve(32*96*2);
  float* scl = (float*)carve(64*4);
  float* sft = (float*)carve(64*4);
  size_t used = (size_t)(p - (char*)d_ws);

  const size_t unit = 4063232ull;             // 32*1024*62*2 bytes per batch per big buffer
  int CB = 16;
  while (CB > 2 && used + 11ull*CB*unit + (2u<<20) > ws_size) CB >>= 1;
  size_t bufB = (size_t)CB * unit;
  u16* xtnm  = (u16*)carve(bufB + 4096);       // +4KB guard: k_final reads l up to 63
  u16* resnm = (u16*)carve(bufB + 4096);
  u16* Xp    = (u16*)carve(bufB);
  u16* Cnm   = (u16*)carve(8*bufB + 4096);
  int Mc = CB * 1984;

  k_cvt_supports<<<dim3(16, 16, 4), 256, 0, stream>>>(sup, sup0, sup1, sup2, Sb8, STb);
  k_prep_weights<<<1, 256, 0, stream>>>(Wg, Wm, W1, Wt, gam, bet, rme, rva,
                                        WgB, WmB, W1B, WtB, scl, sft);
  // squares: Sb8[2j+1] = S_j^2 = S_j * (STb_j)^T, row-major
  k_gemm<1><<<dim3(8, 8, 4), 256, 0, stream>>>(Sb8, (u64)2*NN*NN, STb, (u64)NN*NN,
                                               Sb8 + (size_t)NN*NN, (u64)2*NN*NN, NN);

  for (int b0 = 0; b0 < 16; b0 += CB){
    k_timeconv <<<dim3(1024, CB), 256, 0, stream>>>(x, WtB, bt, xtnm, resnm, b0);
    k_transpose<<<dim3(16, 16, CB), 256, 0, stream>>>(xtnm, Xp);
    k_gemm<0>  <<<dim3(Mc/128, 8, 8), 256, 0, stream>>>(Xp, 0, Sb8, (u64)NN*NN,
                                                        Cnm, (u64)Mc*NN, Mc);
    k_final    <<<dim3(1024, CB), 256, 0, stream>>>(xtnm, resnm, Cnm, WgB, WmB, W1B,
                                                    bg, bm, b1, scl, sft, out, b0, Mc);
  }
}

// Round 5
// 1153.647 us; speedup vs baseline: 1.8721x; 1.0815x over previous
//
#include <hip/hip_runtime.h>
#include <hip/hip_bf16.h>

typedef unsigned short u16;
typedef unsigned int   u32;
typedef unsigned long long u64;
typedef __attribute__((ext_vector_type(8))) __bf16 bf16x8;
typedef __attribute__((ext_vector_type(4))) float  f32x4;
typedef __attribute__((ext_vector_type(4))) u16    u16x4;
typedef __attribute__((ext_vector_type(8))) u16    u16x8;

#define NN   1024
#define TT   64
#define LL   62
#define CIN  32
#define COUT 32

__device__ __forceinline__ u16 f2bf(float f){
  u32 u = __builtin_bit_cast(u32, f);
  return (u16)((u + 0x7fffu + ((u >> 16) & 1u)) >> 16);   // RNE
}
__device__ __forceinline__ bf16x8 ld8(const u16* p){ return *(const bf16x8*)p; }
__device__ __forceinline__ bf16x8 ld8_u32(const u16* p){
  union { bf16x8 v; u32 w[4]; } u;
  #pragma unroll
  for (int e = 0; e < 4; ++e) u.w[e] = *(const u32*)(p + 2*e);
  return u.v;
}

#define MFMA16(a,b,c) __builtin_amdgcn_mfma_f32_16x16x32_bf16((a),(b),(c),0,0,0)
#define GLL16(g,l) __builtin_amdgcn_global_load_lds((const __attribute__((address_space(1))) void*)(g), (__attribute__((address_space(3))) void*)(l), 16, 0, 0)

// ---------- supports -> bf16, row-major slab (2j) + transposed copy ----------
__global__ __launch_bounds__(256) void k_cvt_supports(const float* __restrict__ s0, const float* __restrict__ s1,
                                                      const float* __restrict__ s2, const float* __restrict__ s3,
                                                      u16* __restrict__ Sb8, u16* __restrict__ STb){
  __shared__ u16 t16[64][66];
  const float* srcs[4] = {s0, s1, s2, s3};
  const int j = blockIdx.z;
  const float* sp = srcs[j];
  const int u0 = blockIdx.y * 64, v0 = blockIdx.x * 64;
  const int tid = threadIdx.x;
  u16* SbJ = Sb8 + (size_t)(2*j) * (size_t)(NN*NN);
  u16* STJ = STb + (size_t)j * (size_t)(NN*NN);
  for (int i = tid; i < 4096; i += 256){
    int r = i >> 6, c = i & 63;
    u16 h = f2bf(sp[(size_t)(u0+r)*NN + v0 + c]);
    SbJ[(size_t)(u0+r)*NN + v0 + c] = h;
    t16[r][c] = h;
  }
  __syncthreads();
  for (int i = tid; i < 4096; i += 256){
    int r = i >> 6, c = i & 63;
    STJ[(size_t)(v0+r)*NN + u0 + c] = t16[c][r];
  }
}

// ---------- fold weights, BN constants ----------
__global__ __launch_bounds__(256) void k_prep_weights(const float* __restrict__ Wg, const float* __restrict__ Wm,
    const float* __restrict__ W1, const float* __restrict__ Wt,
    const float* __restrict__ gamma, const float* __restrict__ beta,
    const float* __restrict__ rmean, const float* __restrict__ rvar,
    u16* __restrict__ WgB, u16* __restrict__ WmB, u16* __restrict__ W1B, u16* __restrict__ WtB,
    float* __restrict__ scl, float* __restrict__ sft){
  int tid = threadIdx.x;
  for (int i = tid; i < 64*96; i += 256){
    int o = i / 96, k = i - o*96;
    float v;
    if (k < 32)      v = Wg[o*96 + 3*k] - Wg[o*96 + 3*k + 2];
    else if (k < 64) v = Wg[o*96 + 3*(k-32) + 1];
    else             v = 2.0f * Wg[o*96 + 3*(k-64) + 2];
    WgB[i] = f2bf(v);
  }
  for (int i = tid; i < 64*224; i += 256) WmB[i] = f2bf(Wm[i]);
  for (int i = tid; i < 64*32;  i += 256) W1B[i] = f2bf(W1[i]);
  for (int i = tid; i < 32*96; i += 256){
    int o = i / 96, kk = i - o*96;
    int k = kk >> 5, ci = kk & 31;
    WtB[i] = f2bf(Wt[(o*32 + ci)*3 + k]);
  }
  if (tid < 64){
    float inv = gamma[tid] * rsqrtf(rvar[tid] + 1e-5f);
    scl[tid] = inv;
    sft[tid] = beta[tid] - rmean[tid]*inv;
  }
}

// ---------- time conv via MFMA: xtnm[bl][n][l][c] + resnm ----------
__global__ __launch_bounds__(256) void k_timeconv(const float* __restrict__ x, const u16* __restrict__ WtB,
                                                  const float* __restrict__ bt,
                                                  u16* __restrict__ xtnm, u16* __restrict__ resnm, int b0){
  __shared__ u16 xs[68][34];
  const int n = blockIdx.x, bl = blockIdx.y, b = b0 + bl;
  const int tid = threadIdx.x;
  for (int i = tid; i < 2048; i += 256){
    int ci = i >> 6, t = i & 63;
    xs[t][ci] = f2bf(x[((size_t)(b*CIN + ci)*NN + n)*TT + t]);
  }
  if (tid < 136) xs[64 + tid/34][tid % 34] = 0;
  __syncthreads();
  const int wid = tid >> 6, lane = tid & 63, fc = lane & 15, fh = lane >> 4;
  const int lcol = wid*16 + fc;
  f32x4 acc0 = {0.f,0.f,0.f,0.f}, acc1 = {0.f,0.f,0.f,0.f};
  #pragma unroll
  for (int s = 0; s < 3; ++s){
    bf16x8 bv = ld8_u32(&xs[lcol + s][8*fh]);
    acc0 = MFMA16(ld8(WtB + fc*96        + s*32 + 8*fh), bv, acc0);
    acc1 = MFMA16(ld8(WtB + (16+fc)*96   + s*32 + 8*fh), bv, acc1);
  }
  const size_t nb = ((size_t)bl*NN + n)*1984;
  for (int i = tid; i < LL*4; i += 256){
    int l = i >> 2, oq = i & 3;
    union { bf16x8 v; u16x8 h; } u; u.v = ld8_u32(&xs[2 + l][oq*8]);
    *(u16x8*)(resnm + nb + (size_t)l*32 + oq*8) = u.h;
  }
  if (lcol < LL){
    #pragma unroll
    for (int t = 0; t < 2; ++t){
      const f32x4& a = t ? acc1 : acc0;
      u16x4 pk;
      #pragma unroll
      for (int r = 0; r < 4; ++r) pk[r] = f2bf(a[r] + bt[t*16 + 4*fh + r]);
      *(u16x4*)(xtnm + nb + (size_t)lcol*32 + t*16 + 4*fh) = pk;
    }
  }
}

// ---------- transpose xtnm -> Xp[m=(bl*62+l)*32+c][n] ----------
__global__ __launch_bounds__(256) void k_transpose(const u16* __restrict__ xtnm, u16* __restrict__ Xp){
  __shared__ u32 t32[4][64][17];
  const int nt = blockIdx.x, lq = blockIdx.y, bl = blockIdx.z;
  const int n0 = nt*64, l0 = lq*4;
  const int tid = threadIdx.x;
  for (int i = tid; i < 1024; i += 256){
    int li = i >> 8, rem = i & 255, j = rem >> 2, oq = rem & 3;
    int l = l0 + li;
    if (l < LL){
      const u16* src = xtnm + ((size_t)bl*NN + n0 + j)*1984 + (size_t)l*32 + oq*8;
      u16x8 v = *(const u16x8*)src;
      u32* d = &t32[li][j][oq*4];
      d[0] = (u32)v[0] | ((u32)v[1] << 16);
      d[1] = (u32)v[2] | ((u32)v[3] << 16);
      d[2] = (u32)v[4] | ((u32)v[5] << 16);
      d[3] = (u32)v[6] | ((u32)v[7] << 16);
    }
  }
  __syncthreads();
  for (int i = tid; i < 1024; i += 256){
    int li = i >> 8, rem = i & 255, c = rem >> 3, np = rem & 7;
    int l = l0 + li;
    if (l < LL){
      int cw = c >> 1, hi = c & 1;
      u16x8 o;
      #pragma unroll
      for (int e = 0; e < 8; ++e){
        u32 w = t32[li][np*8 + e][cw];
        o[e] = hi ? (u16)(w >> 16) : (u16)w;
      }
      size_t m = ((size_t)bl*LL + l)*32 + c;
      *(u16x8*)(Xp + m*NN + n0 + np*8) = o;
    }
  }
}

// ---------- small GEMM (squares): C[m][w] = sum_v A[m][v]*B[w][v], row-major out ----------
__global__ __launch_bounds__(256) void k_gemm_sq(const u16* __restrict__ Abase, u64 Ajstr,
                                                 const u16* __restrict__ Bbase, u64 Bjstr,
                                                 u16* __restrict__ outp, u64 Ojstr){
  __shared__ u16 Alds[128*32];
  __shared__ u16 Blds[128*32];
  const int j = blockIdx.z;
  const u16* A  = Abase + (size_t)j * Ajstr;
  const u16* Bm = Bbase + (size_t)j * Bjstr;
  const int m0 = blockIdx.x * 128, w0 = blockIdx.y * 128;
  const int tid = threadIdx.x, wid = tid >> 6;
  const int lane = tid & 63, fc = lane & 15, fh = lane >> 4;
  const int srow = tid >> 2, sch = tid & 3;
  const u16* gA0 = A  + (size_t)(m0 + srow)      * NN + sch*8;
  const u16* gA1 = A  + (size_t)(m0 + srow + 64) * NN + sch*8;
  const u16* gB0 = Bm + (size_t)(w0 + srow)      * NN + sch*8;
  const u16* gB1 = Bm + (size_t)(w0 + srow + 64) * NN + sch*8;
  u16* lA0 = Alds + wid*512;        u16* lA1 = Alds + 2048 + wid*512;
  u16* lB0 = Blds + wid*512;        u16* lB1 = Blds + 2048 + wid*512;
  const int wm = wid >> 1, wn = wid & 1;
  f32x4 acc[4][4] = {};
  for (int v0 = 0; v0 < NN; v0 += 32){
    GLL16(gA0 + v0, lA0);
    GLL16(gA1 + v0, lA1);
    GLL16(gB0 + v0, lB0);
    GLL16(gB1 + v0, lB1);
    __syncthreads();
    bf16x8 af[4], bf_[4];
    #pragma unroll
    for (int i = 0; i < 4; ++i){
      af[i]  = ld8(&Alds[(wm*64 + i*16 + fc)*32 + fh*8]);
      bf_[i] = ld8(&Blds[(wn*64 + i*16 + fc)*32 + fh*8]);
    }
    #pragma unroll
    for (int i = 0; i < 4; ++i)
      #pragma unroll
      for (int q = 0; q < 4; ++q)
        acc[i][q] = MFMA16(af[i], bf_[q], acc[i][q]);
    __syncthreads();
  }
  u16* oj = outp + (size_t)j * Ojstr;
  #pragma unroll
  for (int i = 0; i < 4; ++i){
    int mb = m0 + wm*64 + i*16 + 4*fh;
    #pragma unroll
    for (int q = 0; q < 4; ++q){
      int wc = w0 + wn*64 + q*16 + fc;
      #pragma unroll
      for (int r = 0; r < 4; ++r)
        oj[(size_t)(mb + r)*NN + wc] = f2bf(acc[i][q][r]);
    }
  }
}

// ---------- big graph GEMM: 256x256 tile, BK=32, 4-deep LDS ring, counted vmcnt ----------
// C[j][w*Mc+m] = sum_v Xp[m][v] * B_j[w][v]
__global__ __launch_bounds__(512, 2) void k_gemm8(const u16* __restrict__ Abase,
                                                  const u16* __restrict__ Bbase,
                                                  u16* __restrict__ outp, int Mc){
  __shared__ u16 lds[65536];                 // 128 KiB: A ring 4x8192 u16 at 0, B ring at +32768
  const int tid = threadIdx.x, wid = tid >> 6, lane = tid & 63;
  const int fc = lane & 15, fh = lane >> 4;
  const int wm = wid >> 2, wn = wid & 3;

  // bijective XCD remap, (w,j) fastest within an m-tile for A-panel L2 reuse
  const int nx = gridDim.x;
  int P = blockIdx.x + nx*(blockIdx.y + 4*blockIdx.z);
  int W = (P & 7)*(nx*4) + (P >> 3);
  const int mt = W >> 5, combo = W & 31;
  const int m0 = mt << 8;
  const int j  = combo >> 2;
  const int w0g = (combo & 3) << 8;          // global w base (256 per tile)

  const u16* A  = Abase + (size_t)m0 * NN;
  const u16* Bm = Bbase + (size_t)j * (size_t)(NN*NN) + (size_t)w0g * NN;

  // staging source (pre-swizzled): thread stages 16B; row = (q&1)*128 + (tid>>2)
  const int srow = tid >> 2, sc = tid & 3;
  const int lc = sc ^ ((srow >> 1) & 3);     // swizzle f(row) has period 8; +128 doesn't change it
  const u16* gA = A  + (size_t)srow*NN + lc*8;
  const u16* gB = Bm + (size_t)srow*NN + lc*8;

  auto STAGE = [&](int t, int q){
    const u16* g = ((q < 2) ? gA : gB) + (size_t)(q & 1)*128*NN + t*32;
    int dst = ((q < 2) ? 0 : 32768) + (t & 3)*8192 + (q & 1)*4096 + wid*512;
    GLL16(g, &lds[dst]);
  };

  // fragment LDS offsets (u16 units); offB already carries the +32768 B-region base
  const int swz = (fh ^ ((fc >> 1) & 3)) << 3;
  int offA[8], offB[4];
  #pragma unroll
  for (int i = 0; i < 8; ++i) offA[i] = (wm*128 + i*16 + fc)*32 + swz;
  #pragma unroll
  for (int q = 0; q < 4; ++q) offB[q] = 32768 + (wn*64 + q*16 + fc)*32 + swz;

  f32x4 acc[8][4] = {};

  // prologue: stage tiles 0,1; ensure tile 0 landed
  #pragma unroll
  for (int q = 0; q < 4; ++q) STAGE(0, q);
  #pragma unroll
  for (int q = 0; q < 4; ++q) STAGE(1, q);
  asm volatile("s_waitcnt vmcnt(4)" ::: "memory");
  __builtin_amdgcn_s_barrier();

  #pragma unroll 4
  for (int kt = 0; kt < 32; ++kt){
    const int biA = (kt & 3)*8192;
    const int biB = biA;                     // FIX: base is in offB; was 32768+biA (OOB reads)
    bf16x8 af[4], bf[4], af2[4];
    // ---- phase 0: A-frags 0..3 + all B-frags; stage A-halves of kt+2 ----
    #pragma unroll
    for (int i = 0; i < 4; ++i) af[i] = ld8(&lds[biA + offA[i]]);
    #pragma unroll
    for (int q = 0; q < 4; ++q) bf[q] = ld8(&lds[biB + offB[q]]);
    if (kt < 30){ STAGE(kt+2, 0); STAGE(kt+2, 1); }
    __builtin_amdgcn_s_barrier();
    asm volatile("s_waitcnt lgkmcnt(0)" ::: "memory");
    __builtin_amdgcn_sched_barrier(0);
    __builtin_amdgcn_s_setprio(1);
    #pragma unroll
    for (int i = 0; i < 4; ++i)
      #pragma unroll
      for (int q = 0; q < 4; ++q)
        acc[i][q] = MFMA16(af[i], bf[q], acc[i][q]);
    __builtin_amdgcn_s_setprio(0);
    __builtin_amdgcn_s_barrier();
    // ---- phase 1: A-frags 4..7; stage B-halves of kt+2; counted vmcnt ----
    #pragma unroll
    for (int i = 0; i < 4; ++i) af2[i] = ld8(&lds[biA + offA[4+i]]);
    if (kt < 30){ STAGE(kt+2, 2); STAGE(kt+2, 3); }
    if (kt < 30){ asm volatile("s_waitcnt vmcnt(4)" ::: "memory"); }
    else if (kt == 30){ asm volatile("s_waitcnt vmcnt(0)" ::: "memory"); }
    __builtin_amdgcn_s_barrier();
    asm volatile("s_waitcnt lgkmcnt(0)" ::: "memory");
    __builtin_amdgcn_sched_barrier(0);
    __builtin_amdgcn_s_setprio(1);
    #pragma unroll
    for (int i = 0; i < 4; ++i)
      #pragma unroll
      for (int q = 0; q < 4; ++q)
        acc[4+i][q] = MFMA16(af2[i], bf[q], acc[4+i][q]);
    __builtin_amdgcn_s_setprio(0);
    __builtin_amdgcn_s_barrier();
  }

  // epilogue: node-major bf16 store
  u16* oj = outp + (size_t)j * ((size_t)NN * Mc);
  #pragma unroll
  for (int i = 0; i < 8; ++i){
    int mb = m0 + wm*128 + i*16 + 4*fh;
    #pragma unroll
    for (int q = 0; q < 4; ++q){
      int wc = w0g + wn*64 + q*16 + fc;
      u16x4 pk = { f2bf(acc[i][q][0]), f2bf(acc[i][q][1]), f2bf(acc[i][q][2]), f2bf(acc[i][q][3]) };
      *(u16x4*)&oj[(size_t)wc*Mc + mb] = pk;
    }
  }
}

// ---------- final: LDS-free channel-mix MFMA + GLU + residual + BN ----------
__global__ __launch_bounds__(256) void k_final(
    const u16* __restrict__ xtnm, const u16* __restrict__ resnm, const u16* __restrict__ Cnm,
    const u16* __restrict__ WgB, const u16* __restrict__ WmB, const u16* __restrict__ W1B,
    const float* __restrict__ bg, const float* __restrict__ bm, const float* __restrict__ b1,
    const float* __restrict__ scl, const float* __restrict__ sft,
    float* __restrict__ out, int b0, int Mc){
  const int n = blockIdx.x, bl = blockIdx.y, b = b0 + bl;
  const int tid = threadIdx.x, wid = tid >> 6, lane = tid & 63;
  const int fc = lane & 15, fh = lane >> 4;
  const int lcol = wid*16 + fc;
  const size_t off   = (size_t)lcol*32 + fh*8;
  const size_t nb    = ((size_t)bl*NN + n)*1984;
  const size_t pqoff = (size_t)n*Mc + (size_t)bl*1984 + off;
  const size_t jstr  = (size_t)NN*Mc;

  bf16x8 bX  = ld8(xtnm  + nb + off);
  bf16x8 bR  = ld8(resnm + nb + off);
  bf16x8 bPS = ld8(Cnm            + pqoff);
  bf16x8 bQS = ld8(Cnm + 1*jstr   + pqoff);
  bf16x8 bP0 = ld8(Cnm + 2*jstr   + pqoff);
  bf16x8 bQ0 = ld8(Cnm + 3*jstr   + pqoff);
  bf16x8 bP1 = ld8(Cnm + 4*jstr   + pqoff);
  bf16x8 bQ1 = ld8(Cnm + 5*jstr   + pqoff);
  bf16x8 bP2 = ld8(Cnm + 6*jstr   + pqoff);
  bf16x8 bQ2 = ld8(Cnm + 7*jstr   + pqoff);

  f32x4 acc[12];
  #pragma unroll
  for (int i = 0; i < 12; ++i) acc[i] = (f32x4){0.f, 0.f, 0.f, 0.f};

  {
    const bf16x8 u1b[3] = {bX, bPS, bQS};
    #pragma unroll
    for (int s = 0; s < 3; ++s)
      #pragma unroll
      for (int t = 0; t < 4; ++t)
        acc[t] = MFMA16(ld8(WgB + (t*16 + fc)*96 + s*32 + 8*fh), u1b[s], acc[t]);
  }
  {
    const bf16x8 u2b[7] = {bX, bP0, bQ0, bP1, bQ1, bP2, bQ2};
    #pragma unroll
    for (int s = 0; s < 7; ++s)
      #pragma unroll
      for (int t = 0; t < 4; ++t)
        acc[4+t] = MFMA16(ld8(WmB + (t*16 + fc)*224 + s*32 + 8*fh), u2b[s], acc[4+t]);
  }
  #pragma unroll
  for (int t = 0; t < 4; ++t)
    acc[8+t] = MFMA16(ld8(W1B + (t*16 + fc)*32 + 8*fh), bR, acc[8+t]);

  if (lcol < LL){
    float* ob = out + ((size_t)b*64*NN + n)*LL + lcol;
    #pragma unroll
    for (int t = 0; t < 2; ++t){
      #pragma unroll
      for (int r = 0; r < 4; ++r){
        int os = t*16 + 4*fh + r;
        float u1a = acc[t][r]   + bg[os];
        float u1b = acc[t+2][r] + bg[os+32];
        float s1  = fmaxf(u1a, 0.f) / (1.f + __expf(-u1b));
        float z1  = s1 + acc[8+t][r] + b1[os];
        ob[(size_t)os*(NN*LL)] = z1*scl[os] + sft[os];
        int o2 = 32 + os;
        float u2a = acc[4+t][r] + bm[os];
        float u2b = acc[6+t][r] + bm[os+32];
        float s2  = fmaxf(u2a, 0.f) / (1.f + __expf(-u2b));
        float z2  = s2 + acc[10+t][r] + b1[o2];
        ob[(size_t)o2*(NN*LL)] = z2*scl[o2] + sft[o2];
      }
    }
  }
}

extern "C" void kernel_launch(void* const* d_in, const int* in_sizes, int n_in,
                              void* d_out, int out_size, void* d_ws, size_t ws_size,
                              hipStream_t stream){
  const float* x    = (const float*)d_in[0];
  const float* sup  = (const float*)d_in[1];
  const float* sup0 = (const float*)d_in[2];
  const float* sup1 = (const float*)d_in[3];
  const float* sup2 = (const float*)d_in[4];
  const float* W1   = (const float*)d_in[5];
  const float* b1   = (const float*)d_in[6];
  const float* Wt   = (const float*)d_in[7];
  const float* bt   = (const float*)d_in[8];
  const float* Wg   = (const float*)d_in[9];
  const float* bg   = (const float*)d_in[10];
  const float* Wm   = (const float*)d_in[11];
  const float* bm   = (const float*)d_in[12];
  const float* gam  = (const float*)d_in[13];
  const float* bet  = (const float*)d_in[14];
  const float* rme  = (const float*)d_in[15];
  const float* rva  = (const float*)d_in[16];
  float* out = (float*)d_out;

  char* p = (char*)d_ws;
  auto carve = [&](size_t bytes)->char*{
    char* r = p; p += (bytes + 255) & ~(size_t)255; return r;
  };
  u16*   Sb8 = (u16*)carve((size_t)8*NN*NN*2);   // {S,S^2,A0,A0^2,A1,A1^2,A2,A2^2}
  u16*   STb = (u16*)carve((size_t)4*NN*NN*2);
  u16*   WgB = (u16*)carve(64*96*2);
  u16*   WmB = (u16*)carve(64*224*2);
  u16*   W1B = (u16*)carve(64*32*2);
  u16*   WtB = (u16*)carve(32*96*2);
  float* scl = (float*)carve(64*4);
  float* sft = (float*)carve(64*4);
  size_t used = (size_t)(p - (char*)d_ws);

  const size_t unit = 4063232ull;             // 32*1024*62*2 bytes per batch per big buffer
  int CB = 16;
  while (CB > 4 && used + 11ull*CB*unit + (2u<<20) > ws_size) CB >>= 1;
  size_t bufB = (size_t)CB * unit;
  u16* xtnm  = (u16*)carve(bufB + 4096);
  u16* resnm = (u16*)carve(bufB + 4096);
  u16* Xp    = (u16*)carve(bufB);
  u16* Cnm   = (u16*)carve(8*bufB + 4096);
  int Mc = CB * 1984;                          // divisible by 256 for CB in {4,8,16}

  k_cvt_supports<<<dim3(16, 16, 4), 256, 0, stream>>>(sup, sup0, sup1, sup2, Sb8, STb);
  k_prep_weights<<<1, 256, 0, stream>>>(Wg, Wm, W1, Wt, gam, bet, rme, rva,
                                        WgB, WmB, W1B, WtB, scl, sft);
  // squares: Sb8[2j+1] = S_j * (S_j^T)^T, row-major
  k_gemm_sq<<<dim3(8, 8, 4), 256, 0, stream>>>(Sb8, (u64)2*NN*NN, STb, (u64)NN*NN,
                                               Sb8 + (size_t)NN*NN, (u64)2*NN*NN);

  for (int b0 = 0; b0 < 16; b0 += CB){
    k_timeconv <<<dim3(1024, CB), 256, 0, stream>>>(x, WtB, bt, xtnm, resnm, b0);
    k_transpose<<<dim3(16, 16, CB), 256, 0, stream>>>(xtnm, Xp);
    k_gemm8    <<<dim3(Mc/256, 4, 8), 512, 0, stream>>>(Xp, Sb8, Cnm, Mc);
    k_final    <<<dim3(1024, CB), 256, 0, stream>>>(xtnm, resnm, Cnm, WgB, WmB, W1B,
                                                    bg, bm, b1, scl, sft, out, b0, Mc);
  }
}